// Round 8
// baseline (133.467 us; speedup 1.0000x reference)
//
#include <hip/hip_runtime.h>
#include <hip/hip_bf16.h>
#include <math.h>

// Shapes (fixed by reference)
#define B_ 4
#define L_ 256
#define H_ 768
#define P_ 32896   // L*(L+1)/2
#define N_ 1536    // 2*H
#define K_ 768
#define M_ 1024    // B*L

typedef __attribute__((ext_vector_type(4))) float f32x4;
typedef __attribute__((ext_vector_type(8))) short s16x8;

__device__ __forceinline__ unsigned pack_bf16(float x, float y) {
    __hip_bfloat16 hx = __float2bfloat16(x);   // RTN
    __hip_bfloat16 hy = __float2bfloat16(y);
    const unsigned short ux = *(const unsigned short*)&hx;
    const unsigned short uy = *(const unsigned short*)&hy;
    return (unsigned)ux | ((unsigned)uy << 16);
}

// ---------------------------------------------------------------------------
// MFMA GEMM (unchanged from R4, ~8-10 us): T[m][n] = sum_k A[m][k]*Wsel[n][k]
// (+ bias for n < H). 64x64 tile, BK=64, 4 waves, XOR-swizzled LDS.
// ---------------------------------------------------------------------------
__global__ __launch_bounds__(256) void gemm_uv_mfma(
        const float* __restrict__ A, const float* __restrict__ W,
        const float* __restrict__ bias, float* __restrict__ T) {
    __shared__ __align__(16) char As[64 * 128];   // 64 rows x 64 bf16
    __shared__ __align__(16) char Bs[64 * 128];

    const int tid = threadIdx.x;
    const int bm = blockIdx.x * 64;
    const int bn = blockIdx.y * 64;
    const int lane = tid & 63;
    const int wave = tid >> 6;

    const int sr = tid >> 4;            // 0..15
    const int sk = (tid & 15) * 4;      // 0..60
    const float* wbase = (bn < H_) ? (W + (size_t)bn * N_)
                                   : (W + (size_t)(bn - H_) * N_ + H_);

    const int wm = (wave & 1) * 32;
    const int wn = (wave >> 1) * 32;
    const int l15 = lane & 15;
    const int l4  = lane >> 4;

    f32x4 acc[2][2] = {};

    for (int kt = 0; kt < K_; kt += 64) {
        __syncthreads();
#pragma unroll
        for (int ph = 0; ph < 4; ++ph) {
            const int row = ph * 16 + sr;
            const float4 av = *(const float4*)(A + (size_t)(bm + row) * K_ + kt + sk);
            const float4 bv = *(const float4*)(wbase + (size_t)row * N_ + kt + sk);
            const int chunk = sk >> 3;
            const int sub   = (sk & 4) ? 8 : 0;
            const int boff  = row * 128 + ((chunk ^ (row & 7)) * 16) + sub;
            *(uint2*)(As + boff) = make_uint2(pack_bf16(av.x, av.y), pack_bf16(av.z, av.w));
            *(uint2*)(Bs + boff) = make_uint2(pack_bf16(bv.x, bv.y), pack_bf16(bv.z, bv.w));
        }
        __syncthreads();
#pragma unroll
        for (int ks = 0; ks < 2; ++ks) {
            s16x8 af[2], bf[2];
#pragma unroll
            for (int mi = 0; mi < 2; ++mi) {
                const int row = wm + mi * 16 + l15;
                const int chunk = (ks * 4 + l4) ^ (row & 7);
                af[mi] = *(const s16x8*)(As + row * 128 + chunk * 16);
            }
#pragma unroll
            for (int ni = 0; ni < 2; ++ni) {
                const int row = wn + ni * 16 + l15;
                const int chunk = (ks * 4 + l4) ^ (row & 7);
                bf[ni] = *(const s16x8*)(Bs + row * 128 + chunk * 16);
            }
#pragma unroll
            for (int mi = 0; mi < 2; ++mi)
#pragma unroll
                for (int ni = 0; ni < 2; ++ni)
                    acc[mi][ni] = __builtin_amdgcn_mfma_f32_16x16x32_bf16(
                        af[mi], bf[ni], acc[mi][ni], 0, 0, 0);
        }
    }

#pragma unroll
    for (int mi = 0; mi < 2; ++mi)
#pragma unroll
        for (int ni = 0; ni < 2; ++ni) {
            const int gm0 = bm + wm + mi * 16 + l4 * 4;
            const int gn  = bn + wn + ni * 16 + l15;
            const float badd = (gn < H_) ? bias[gn] : 0.0f;
#pragma unroll
            for (int r = 0; r < 4; ++r)
                T[(size_t)(gm0 + r) * N_ + gn] = acc[mi][ni][r] + badd;
        }
}

// tanh(x) = 1 - 2/(exp2(2*log2e*x)+1); exact at +-inf. 5 VALU ops.
__device__ __forceinline__ float fast_tanh(float x) {
    const float e = __builtin_amdgcn_exp2f(x * 2.885390081777926815f);
    const float r = __builtin_amdgcn_rcpf(e + 1.0f);
    return fmaf(-2.0f, r, 1.0f);
}

__device__ __forceinline__ f32x4 tanh4(f32x4 u, f32x4 v) {
    f32x4 o;
    o.x = fast_tanh(u.x + v.x);
    o.y = fast_tanh(u.y + v.y);
    o.z = fast_tanh(u.z + v.z);
    o.w = fast_tanh(u.w + v.w);
    return o;
}

// ---------------------------------------------------------------------------
// Epilogue, sequential-write form: out[b,p(i,j),h] = tanh(U'[b,i]+V[b,j])[h]
// Identical to R7 except REGULAR stores (A/B vs R7's nontemporal): fillBuffer
// proves the L2 write-combining path sustains 6.8 TB/s at 11% occupancy;
// testing whether the NT/L2-bypass path is the 2x write-BW haircut.
// Block = (b, row-pair (i1, i2=255-i1), j-half); 257 rows/pair; 1024 blocks.
// p(i,j) = i*(513-i)/2 + j - i.
// ---------------------------------------------------------------------------
__global__ __launch_bounds__(192) void handshake_epilogue_seq(
        const float* __restrict__ T,
        float* __restrict__ out) {
    const int half = blockIdx.x;        // 0..1
    const int i1   = blockIdx.y;        // 0..127
    const int b    = blockIdx.z;        // 0..3
    const int i2   = 255 - i1;          // partner row, i2 > i1 always

    // j-range split balancing write count (257 total):
    const int j_mid = (i1 <= 63) ? (i1 + 128) : 191;
    const int jlo = half ? j_mid : i1;
    const int jhi = half ? 256 : j_mid;

    const int h = threadIdx.x * 4;      // 192 threads * 4 = 768 floats/row
    const float* Tb = T + (size_t)b * L_ * N_;
    const float* Vb = Tb + H_ + h;      // V row j at Vb + j*N_

    const f32x4 u1 = *(const f32x4*)(Tb + (size_t)i1 * N_ + h);
    const f32x4 u2 = *(const f32x4*)(Tb + (size_t)i2 * N_ + h);

    const size_t off1 = (size_t)i1 * (2 * L_ + 1 - i1) / 2;
    const size_t off2 = (size_t)i2 * (2 * L_ + 1 - i2) / 2;
    // o1 writes every j in [jlo, jhi): position off1 + (j - i1).
    float* o1 = out + ((size_t)b * P_ + off1 + (size_t)(jlo - i1)) * H_ + h;
    // o2 writes only j >= i2; first write at j = max(jlo, i2).
    const int j2first = (jlo > i2) ? jlo : i2;
    float* o2 = out + ((size_t)b * P_ + off2 + (size_t)(j2first - i2)) * H_ + h;

    // Depth-2 V prefetch (named regs, no runtime-indexed arrays).
    f32x4 v0 = *(const f32x4*)(Vb + (size_t)jlo * N_);
    f32x4 v1 = (jlo + 1 < 256) ? *(const f32x4*)(Vb + (size_t)(jlo + 1) * N_) : v0;

    for (int j = jlo; j < jhi; ++j) {
        const f32x4 vc = v0;
        v0 = v1;
        if (j + 2 < 256)                 // uniform branch
            v1 = *(const f32x4*)(Vb + (size_t)(j + 2) * N_);

        *(f32x4*)o1 = tanh4(u1, vc);
        o1 += H_;
        if (j >= i2) {                   // uniform branch
            *(f32x4*)o2 = tanh4(u2, vc);
            o2 += H_;
        }
    }
}

extern "C" void kernel_launch(void* const* d_in, const int* in_sizes, int n_in,
                              void* d_out, int out_size, void* d_ws, size_t ws_size,
                              hipStream_t stream) {
    const float* seq  = (const float*)d_in[0];   // (B, L, H) fp32
    const float* W    = (const float*)d_in[1];   // (H, 2H) fp32
    const float* bias = (const float*)d_in[2];   // (H,) fp32
    float* out = (float*)d_out;                  // (B, P, H) fp32
    float* T   = (float*)d_ws;                   // (B*L, 2H) fp32 = 6.3 MB

    dim3 g1(M_ / 64, N_ / 64);                   // 16 x 24 = 384 blocks
    gemm_uv_mfma<<<g1, 256, 0, stream>>>(seq, W, bias, T);

    dim3 g2(2, 128, B_);                         // (j-half, pair, b) = 1024 blocks
    handshake_epilogue_seq<<<g2, 192, 0, stream>>>(T, out);
}

// Round 9
// 123.324 us; speedup vs baseline: 1.0822x; 1.0822x over previous
//
#include <hip/hip_runtime.h>
#include <hip/hip_bf16.h>
#include <math.h>

// Shapes (fixed by reference)
#define B_ 4
#define L_ 256
#define H_ 768
#define P_ 32896   // L*(L+1)/2
#define N_ 1536    // 2*H
#define K_ 768
#define M_ 1024    // B*L

typedef __attribute__((ext_vector_type(4))) float f32x4;
typedef __attribute__((ext_vector_type(8))) short s16x8;

__device__ __forceinline__ unsigned pack_bf16(float x, float y) {
    __hip_bfloat16 hx = __float2bfloat16(x);   // RTN
    __hip_bfloat16 hy = __float2bfloat16(y);
    const unsigned short ux = *(const unsigned short*)&hx;
    const unsigned short uy = *(const unsigned short*)&hy;
    return (unsigned)ux | ((unsigned)uy << 16);
}

// ---------------------------------------------------------------------------
// MFMA GEMM (unchanged from R4, est <10 us): T[m][n] = sum_k A[m][k]*Wsel[n][k]
// (+ bias for n < H). 64x64 tile, BK=64, 4 waves, XOR-swizzled LDS.
// ---------------------------------------------------------------------------
__global__ __launch_bounds__(256) void gemm_uv_mfma(
        const float* __restrict__ A, const float* __restrict__ W,
        const float* __restrict__ bias, float* __restrict__ T) {
    __shared__ __align__(16) char As[64 * 128];   // 64 rows x 64 bf16
    __shared__ __align__(16) char Bs[64 * 128];

    const int tid = threadIdx.x;
    const int bm = blockIdx.x * 64;
    const int bn = blockIdx.y * 64;
    const int lane = tid & 63;
    const int wave = tid >> 6;

    const int sr = tid >> 4;            // 0..15
    const int sk = (tid & 15) * 4;      // 0..60
    const float* wbase = (bn < H_) ? (W + (size_t)bn * N_)
                                   : (W + (size_t)(bn - H_) * N_ + H_);

    const int wm = (wave & 1) * 32;
    const int wn = (wave >> 1) * 32;
    const int l15 = lane & 15;
    const int l4  = lane >> 4;

    f32x4 acc[2][2] = {};

    for (int kt = 0; kt < K_; kt += 64) {
        __syncthreads();
#pragma unroll
        for (int ph = 0; ph < 4; ++ph) {
            const int row = ph * 16 + sr;
            const float4 av = *(const float4*)(A + (size_t)(bm + row) * K_ + kt + sk);
            const float4 bv = *(const float4*)(wbase + (size_t)row * N_ + kt + sk);
            const int chunk = sk >> 3;
            const int sub   = (sk & 4) ? 8 : 0;
            const int boff  = row * 128 + ((chunk ^ (row & 7)) * 16) + sub;
            *(uint2*)(As + boff) = make_uint2(pack_bf16(av.x, av.y), pack_bf16(av.z, av.w));
            *(uint2*)(Bs + boff) = make_uint2(pack_bf16(bv.x, bv.y), pack_bf16(bv.z, bv.w));
        }
        __syncthreads();
#pragma unroll
        for (int ks = 0; ks < 2; ++ks) {
            s16x8 af[2], bf[2];
#pragma unroll
            for (int mi = 0; mi < 2; ++mi) {
                const int row = wm + mi * 16 + l15;
                const int chunk = (ks * 4 + l4) ^ (row & 7);
                af[mi] = *(const s16x8*)(As + row * 128 + chunk * 16);
            }
#pragma unroll
            for (int ni = 0; ni < 2; ++ni) {
                const int row = wn + ni * 16 + l15;
                const int chunk = (ks * 4 + l4) ^ (row & 7);
                bf[ni] = *(const s16x8*)(Bs + row * 128 + chunk * 16);
            }
#pragma unroll
            for (int mi = 0; mi < 2; ++mi)
#pragma unroll
                for (int ni = 0; ni < 2; ++ni)
                    acc[mi][ni] = __builtin_amdgcn_mfma_f32_16x16x32_bf16(
                        af[mi], bf[ni], acc[mi][ni], 0, 0, 0);
        }
    }

#pragma unroll
    for (int mi = 0; mi < 2; ++mi)
#pragma unroll
        for (int ni = 0; ni < 2; ++ni) {
            const int gm0 = bm + wm + mi * 16 + l4 * 4;
            const int gn  = bn + wn + ni * 16 + l15;
            const float badd = (gn < H_) ? bias[gn] : 0.0f;
#pragma unroll
            for (int r = 0; r < 4; ++r)
                T[(size_t)(gm0 + r) * N_ + gn] = acc[mi][ni][r] + badd;
        }
}

// tanh(x) = 1 - 2/(exp2(2*log2e*x)+1); exact at +-inf. 5 VALU ops.
__device__ __forceinline__ float fast_tanh(float x) {
    const float e = __builtin_amdgcn_exp2f(x * 2.885390081777926815f);
    const float r = __builtin_amdgcn_rcpf(e + 1.0f);
    return fmaf(-2.0f, r, 1.0f);
}

__device__ __forceinline__ f32x4 tanh4(f32x4 u, f32x4 v) {
    f32x4 o;
    o.x = fast_tanh(u.x + v.x);
    o.y = fast_tanh(u.y + v.y);
    o.z = fast_tanh(u.z + v.z);
    o.w = fast_tanh(u.w + v.w);
    return o;
}

// ---------------------------------------------------------------------------
// Epilogue = R7's sequential-write pair structure + XCD-AFFINITY SWIZZLE.
// The 404 MB of V re-reads were missing L2 (per-XCD working set was 4 batches
// x 3 MB = 12 MB > 4 MiB L2) and streaming over the HBM fabric alongside the
// 404 MB write stream -> 808 MB / 6.4 TB/s ~ 126 us = measured. Remap the 1D
// block id so batch b's 256 blocks land on XCDs {2b, 2b+1} (empirical
// xcd = bid % 8 round-robin): per-XCD V working set = 3 MB < 4 MiB L2 ->
// V reads become L2 hits. NT stores keep the write stream out of L2.
//   bid = 8*i1 + 2*b + half   (bijective over [0,1024))
// p(i,j) = i*(513-i)/2 + j - i.
// ---------------------------------------------------------------------------
__global__ __launch_bounds__(192) void handshake_epilogue_seq(
        const float* __restrict__ T,
        float* __restrict__ out) {
    const int bid  = blockIdx.x;        // 0..1023
    const int b    = (bid & 7) >> 1;    // XCD-affine: xcd = bid%8 = 2b+half
    const int half = bid & 1;
    const int i1   = bid >> 3;          // 0..127
    const int i2   = 255 - i1;          // partner row, i2 > i1 always

    // j-range split balancing write count (257 total):
    const int j_mid = (i1 <= 63) ? (i1 + 128) : 191;
    const int jlo = half ? j_mid : i1;
    const int jhi = half ? 256 : j_mid;

    const int h = threadIdx.x * 4;      // 192 threads * 4 = 768 floats/row
    const float* Tb = T + (size_t)b * L_ * N_;
    const float* Vb = Tb + H_ + h;      // V row j at Vb + j*N_

    const f32x4 u1 = *(const f32x4*)(Tb + (size_t)i1 * N_ + h);
    const f32x4 u2 = *(const f32x4*)(Tb + (size_t)i2 * N_ + h);

    const size_t off1 = (size_t)i1 * (2 * L_ + 1 - i1) / 2;
    const size_t off2 = (size_t)i2 * (2 * L_ + 1 - i2) / 2;
    // o1 writes every j in [jlo, jhi): position off1 + (j - i1).
    float* o1 = out + ((size_t)b * P_ + off1 + (size_t)(jlo - i1)) * H_ + h;
    // o2 writes only j >= i2; first write at j = max(jlo, i2).
    const int j2first = (jlo > i2) ? jlo : i2;
    float* o2 = out + ((size_t)b * P_ + off2 + (size_t)(j2first - i2)) * H_ + h;

    // Depth-2 V prefetch (named regs, no runtime-indexed arrays).
    f32x4 v0 = *(const f32x4*)(Vb + (size_t)jlo * N_);
    f32x4 v1 = (jlo + 1 < 256) ? *(const f32x4*)(Vb + (size_t)(jlo + 1) * N_) : v0;

    for (int j = jlo; j < jhi; ++j) {
        const f32x4 vc = v0;
        v0 = v1;
        if (j + 2 < 256)                 // uniform branch
            v1 = *(const f32x4*)(Vb + (size_t)(j + 2) * N_);

        __builtin_nontemporal_store(tanh4(u1, vc), (f32x4*)o1);
        o1 += H_;
        if (j >= i2) {                   // uniform branch
            __builtin_nontemporal_store(tanh4(u2, vc), (f32x4*)o2);
            o2 += H_;
        }
    }
}

extern "C" void kernel_launch(void* const* d_in, const int* in_sizes, int n_in,
                              void* d_out, int out_size, void* d_ws, size_t ws_size,
                              hipStream_t stream) {
    const float* seq  = (const float*)d_in[0];   // (B, L, H) fp32
    const float* W    = (const float*)d_in[1];   // (H, 2H) fp32
    const float* bias = (const float*)d_in[2];   // (H,) fp32
    float* out = (float*)d_out;                  // (B, P, H) fp32
    float* T   = (float*)d_ws;                   // (B*L, 2H) fp32 = 6.3 MB

    dim3 g1(M_ / 64, N_ / 64);                   // 16 x 24 = 384 blocks
    gemm_uv_mfma<<<g1, 256, 0, stream>>>(seq, W, bias, T);

    handshake_epilogue_seq<<<1024, 192, 0, stream>>>(T, out);
}